// Round 15
// baseline (101.109 us; speedup 1.0000x reference)
//
#include <hip/hip_runtime.h>

#define LOG2E 1.4426950408889634f
#define K_SCALE 2.8853900817779268f   // 2*log2(e)

typedef __attribute__((ext_vector_type(8))) short bf16x8;
typedef __attribute__((ext_vector_type(4))) float f32x4;

constexpr int Bn = 4, LXn = 384, LYn = 384, Hn = 256, Fn = 512;

__device__ inline unsigned short bf16rn(float f) {
  unsigned u = __builtin_bit_cast(unsigned, f);
  u += 0x7fff + ((u >> 16) & 1);             // round-to-nearest-even
  return (unsigned short)(u >> 16);
}
__device__ inline float bf16tof(unsigned short h) {
  return __builtin_bit_cast(float, (unsigned)h << 16);
}

// ---------------------------------------------------------------- kernel 1
// (R14 gemm5 verbatim — single barrier per kc via LDS dbuf)
__global__ __launch_bounds__(256) void gemm5(
    const float* __restrict__ x, const float* __restrict__ y,
    const float* __restrict__ Wm, float* __restrict__ ey, float* __restrict__ exT,
    unsigned short* __restrict__ xTh, unsigned short* __restrict__ xTl)
{
  __shared__ char smem[55296];
  const int tid = threadIdx.x;
  const int bid = blockIdx.x;

  if (bid >= 384) {                       // ---- transpose/split path ----
    float* T = (float*)smem;              // [64][65]
    const int pid = bid - 384;
    const int b = pid / 48, t = pid % 48;
    const int l0 = (t / 8) * 64, f0 = (t % 8) * 64;
    const int r = tid >> 2, cq = (tid & 3) * 16;
    const float* xp = x + ((size_t)(b * LXn + l0 + r)) * Fn + f0 + cq;
    #pragma unroll
    for (int q = 0; q < 4; ++q) {
      float4 v = *(const float4*)(xp + q * 4);
      T[r * 65 + cq + q * 4 + 0] = v.x; T[r * 65 + cq + q * 4 + 1] = v.y;
      T[r * 65 + cq + q * 4 + 2] = v.z; T[r * 65 + cq + q * 4 + 3] = v.w;
    }
    __syncthreads();
    const int fr = tid >> 2, lq = (tid & 3) * 16;
    unsigned short hi[16], lo[16];
    #pragma unroll
    for (int i = 0; i < 16; ++i) {
      float v = T[(lq + i) * 65 + fr];
      hi[i] = bf16rn(v);
      lo[i] = bf16rn(v - bf16tof(hi[i]));
    }
    size_t o = ((size_t)(b * Fn + f0 + fr)) * LXn + l0 + lq;
    *(uint4*)&xTh[o] = *(uint4*)&hi[0]; *(uint4*)&xTh[o + 8] = *(uint4*)&hi[8];
    *(uint4*)&xTl[o] = *(uint4*)&lo[0]; *(uint4*)&xTl[o + 8] = *(uint4*)&lo[8];
    return;
  }

  // ---- MFMA GEMM path, 32x64 tile, double-buffered ----
  unsigned short* S0 = (unsigned short*)smem;

  const float *Ap, *Bp; float ksc; bool jobA;
  int m0, n0;
  if (bid < 192) { jobA = true;  m0 = (bid % 48) * 32; n0 = (bid / 48) * 64;
                   Ap = y;  Bp = Wm; ksc = -K_SCALE; }
  else { int t = bid - 192; jobA = false; m0 = (t % 8) * 32; n0 = (t / 8) * 64;
                   Ap = Wm; Bp = x;  ksc =  K_SCALE; }

  const int rA = tid >> 3, kA = (tid & 7) * 8;
  const int rB = tid >> 2, kB = (tid & 3) * 16;
  const int w = tid >> 6, lane = tid & 63, quad = lane >> 4, l15 = lane & 15;
  const int mo = (w & 1) * 16, no = (w >> 1) * 32;
  f32x4 acc[2] = {};

  const float* apt = Ap + ((size_t)(m0 + rA)) * Fn + kA;
  const float* bpt = Bp + ((size_t)(n0 + rB)) * Fn + kB;
  float4 aR0 = *(const float4*)(apt),     aR1 = *(const float4*)(apt + 4);
  float4 bR0 = *(const float4*)(bpt),     bR1 = *(const float4*)(bpt + 4);
  float4 bR2 = *(const float4*)(bpt + 8), bR3 = *(const float4*)(bpt + 12);

  {
    unsigned short* D = S0;
    float av[8] = {aR0.x, aR0.y, aR0.z, aR0.w, aR1.x, aR1.y, aR1.z, aR1.w};
    unsigned short hi[16], lo[16];
    #pragma unroll
    for (int i = 0; i < 8; ++i) { hi[i] = bf16rn(av[i]); lo[i] = bf16rn(av[i] - bf16tof(hi[i])); }
    *(uint4*)&D[rA * 72 + kA] = *(uint4*)&hi[0];
    *(uint4*)&D[2304 + rA * 72 + kA] = *(uint4*)&lo[0];
    float bv[16] = {bR0.x, bR0.y, bR0.z, bR0.w, bR1.x, bR1.y, bR1.z, bR1.w,
                    bR2.x, bR2.y, bR2.z, bR2.w, bR3.x, bR3.y, bR3.z, bR3.w};
    #pragma unroll
    for (int i = 0; i < 16; ++i) { hi[i] = bf16rn(bv[i]); lo[i] = bf16rn(bv[i] - bf16tof(hi[i])); }
    *(uint4*)&D[4608 + rB * 72 + kB] = *(uint4*)&hi[0];
    *(uint4*)&D[4608 + rB * 72 + kB + 8] = *(uint4*)&hi[8];
    *(uint4*)&D[9216 + rB * 72 + kB] = *(uint4*)&lo[0];
    *(uint4*)&D[9216 + rB * 72 + kB + 8] = *(uint4*)&lo[8];
  }
  __syncthreads();

  for (int kc = 0; kc < Fn; kc += 64) {
    const int cur = (kc >> 6) & 1;
    unsigned short* Sc = S0 + cur * 13824;
    unsigned short* Sn = S0 + (cur ^ 1) * 13824;
    const bool more = (kc + 64) < Fn;
    if (more) {
      aR0 = *(const float4*)(apt + kc + 64);     aR1 = *(const float4*)(apt + kc + 68);
      bR0 = *(const float4*)(bpt + kc + 64);     bR1 = *(const float4*)(bpt + kc + 68);
      bR2 = *(const float4*)(bpt + kc + 72);     bR3 = *(const float4*)(bpt + kc + 76);
    }
    #pragma unroll
    for (int ko = 0; ko < 64; ko += 32) {
      const int ra = (mo + l15) * 72 + ko + quad * 8;
      bf16x8 a_h = *(const bf16x8*)&Sc[ra];
      bf16x8 a_l = *(const bf16x8*)&Sc[2304 + ra];
      #pragma unroll
      for (int nj = 0; nj < 2; ++nj) {
        const int rb = (no + nj * 16 + l15) * 72 + ko + quad * 8;
        bf16x8 b_h = *(const bf16x8*)&Sc[4608 + rb];
        bf16x8 b_l = *(const bf16x8*)&Sc[9216 + rb];
        acc[nj] = __builtin_amdgcn_mfma_f32_16x16x32_bf16(a_h, b_h, acc[nj], 0, 0, 0);
        acc[nj] = __builtin_amdgcn_mfma_f32_16x16x32_bf16(a_l, b_h, acc[nj], 0, 0, 0);
        acc[nj] = __builtin_amdgcn_mfma_f32_16x16x32_bf16(a_h, b_l, acc[nj], 0, 0, 0);
      }
    }
    if (more) {
      float av[8] = {aR0.x, aR0.y, aR0.z, aR0.w, aR1.x, aR1.y, aR1.z, aR1.w};
      unsigned short hi[16], lo[16];
      #pragma unroll
      for (int i = 0; i < 8; ++i) { hi[i] = bf16rn(av[i]); lo[i] = bf16rn(av[i] - bf16tof(hi[i])); }
      *(uint4*)&Sn[rA * 72 + kA] = *(uint4*)&hi[0];
      *(uint4*)&Sn[2304 + rA * 72 + kA] = *(uint4*)&lo[0];
      float bv[16] = {bR0.x, bR0.y, bR0.z, bR0.w, bR1.x, bR1.y, bR1.z, bR1.w,
                      bR2.x, bR2.y, bR2.z, bR2.w, bR3.x, bR3.y, bR3.z, bR3.w};
      #pragma unroll
      for (int i = 0; i < 16; ++i) { hi[i] = bf16rn(bv[i]); lo[i] = bf16rn(bv[i] - bf16tof(hi[i])); }
      *(uint4*)&Sn[4608 + rB * 72 + kB] = *(uint4*)&hi[0];
      *(uint4*)&Sn[4608 + rB * 72 + kB + 8] = *(uint4*)&hi[8];
      *(uint4*)&Sn[9216 + rB * 72 + kB] = *(uint4*)&lo[0];
      *(uint4*)&Sn[9216 + rB * 72 + kB + 8] = *(uint4*)&lo[8];
    }
    __syncthreads();
  }
  #pragma unroll
  for (int nj = 0; nj < 2; ++nj)
    #pragma unroll
    for (int rr = 0; rr < 4; ++rr) {
      int row = m0 + mo + quad * 4 + rr;
      int col = n0 + no + nj * 16 + l15;
      float val = __builtin_amdgcn_exp2f(ksc * acc[nj][rr]);
      if (jobA) ey[(size_t)row * Hn + col] = val;
      else {
        int bb = col / LXn, l = col % LXn;
        exT[(size_t)bb * Hn * LXn + (size_t)row * LXn + l] = val;
      }
    }
}

// ---------------------------------------------------------------- kernel 2
// score_part: score_v2's proven loop, h-split 2-way -> 512 blocks = 2/CU.
// blockIdx.x: bit0 = h-half, bits1+ = j-group. Writes f32 partial s.
__global__ __launch_bounds__(768) void score_part(
    const float* __restrict__ exT, const float* __restrict__ ey,
    const float* __restrict__ vm, float* __restrict__ partS)
{
  __shared__ float ey6[6 * 128];
  __shared__ float vms[128];
  __shared__ __align__(16) float part[4 * 6 * 384];   // ~37 KB, 2 blocks/CU ok

  const int tid = threadIdx.x;
  const int b = blockIdx.y;
  const int half = blockIdx.x & 1, j0 = (blockIdx.x >> 1) * 6;
  const int hoff = half * 128;
  const int lq = tid % 96, hg = tid / 96;
  const int hb = hg * 16;                 // local h-base within the half

  for (int i = tid; i < 6 * 128; i += 768)
    ey6[i] = ey[(size_t)(b * LYn + j0 + (i >> 7)) * Hn + hoff + (i & 127)];
  if (tid < 128) vms[tid] = -2.0f * vm[hoff + tid];
  __syncthreads();

  const float* exb = exT + (size_t)b * Hn * LXn + (size_t)(hoff + hb) * LXn + lq * 4;
  float acc[6][4] = {};

  for (int hs = 0; hs < 16; hs += 8) {
    float4 e[8];
    #pragma unroll
    for (int u = 0; u < 8; ++u) e[u] = *(const float4*)(exb + (size_t)(hs + u) * LXn);
    float4 va = *(const float4*)&vms[hb + hs];
    float4 vb = *(const float4*)&vms[hb + hs + 4];
    #pragma unroll
    for (int j = 0; j < 6; ++j) {
      float4 ya = *(const float4*)&ey6[j * 128 + hb + hs];
      float4 yb = *(const float4*)&ey6[j * 128 + hb + hs + 4];
      #pragma unroll
      for (int i = 0; i < 4; ++i) {
        {
          float A = fmaf(((const float*)&e[0])[i], ya.x, 1.f);
          float B = fmaf(((const float*)&e[1])[i], ya.y, 1.f);
          float C = fmaf(((const float*)&e[2])[i], ya.z, 1.f);
          float D = fmaf(((const float*)&e[3])[i], ya.w, 1.f);
          float AB = A * B, CD = C * D;
          float n1 = fmaf(va.y, A, va.x * B), n2 = fmaf(va.w, C, va.z * D);
          float num = fmaf(n2, AB, n1 * CD);
          acc[j][i] = fmaf(num, __builtin_amdgcn_rcpf(AB * CD), acc[j][i]);
        }
        {
          float A = fmaf(((const float*)&e[4])[i], yb.x, 1.f);
          float B = fmaf(((const float*)&e[5])[i], yb.y, 1.f);
          float C = fmaf(((const float*)&e[6])[i], yb.z, 1.f);
          float D = fmaf(((const float*)&e[7])[i], yb.w, 1.f);
          float AB = A * B, CD = C * D;
          float n1 = fmaf(vb.y, A, vb.x * B), n2 = fmaf(vb.w, C, vb.z * D);
          float num = fmaf(n2, AB, n1 * CD);
          acc[j][i] = fmaf(num, __builtin_amdgcn_rcpf(AB * CD), acc[j][i]);
        }
      }
    }
  }

  // fold 8 hg-planes -> 4 -> 1, write f32 partials
  if (hg >= 4) {
    #pragma unroll
    for (int j = 0; j < 6; ++j)
      *(float4*)&part[((hg - 4) * 6 + j) * 384 + lq * 4] = *(const float4*)&acc[j][0];
  }
  __syncthreads();
  if (hg < 4) {
    #pragma unroll
    for (int j = 0; j < 6; ++j) {
      float4 o = *(const float4*)&part[(hg * 6 + j) * 384 + lq * 4];
      acc[j][0] += o.x; acc[j][1] += o.y; acc[j][2] += o.z; acc[j][3] += o.w;
      *(float4*)&part[(hg * 6 + j) * 384 + lq * 4] = *(const float4*)&acc[j][0];
    }
  }
  __syncthreads();
  if (tid < 576) {
    const int j = tid / 96;
    float4 s4 = make_float4(0, 0, 0, 0);
    #pragma unroll
    for (int p = 0; p < 4; ++p) {
      float4 o = *(const float4*)&part[(p * 6 + j) * 384 + lq * 4];
      s4.x += o.x; s4.y += o.y; s4.z += o.z; s4.w += o.w;
    }
    *(float4*)&partS[((size_t)half * 1536 + b * LYn + j0 + j) * 384 + lq * 4] = s4;
  }
}

// ---------------------------------------------------------------- kernel 3
// sm_comb: sum 2 h-halves, no-max softmax per row (one wave per row), bf16 a.
__global__ __launch_bounds__(512) void sm_comb(
    const float* __restrict__ partS, unsigned short* __restrict__ ahi)
{
  const int tid = threadIdx.x;
  const int wid = tid >> 6, lane = tid & 63;
  const int row = blockIdx.x * 8 + wid;              // [0, 1536)
  const float* p0 = partS + (size_t)row * 384;
  const float* p1 = p0 + (size_t)1536 * 384;
  float e[6], tot = 0.f;
  #pragma unroll
  for (int q = 0; q < 6; ++q) {
    float s = p0[lane + 64 * q] + p1[lane + 64 * q];
    e[q] = __builtin_amdgcn_exp2f(s * LOG2E);
    tot += e[q];
  }
  #pragma unroll
  for (int off = 32; off; off >>= 1) tot += __shfl_xor(tot, off);
  float r = __builtin_amdgcn_rcpf(tot);
  unsigned short* arow = ahi + (size_t)row * 384;
  #pragma unroll
  for (int q = 0; q < 6; ++q) arow[lane + 64 * q] = bf16rn(e[q] * r);
}

// ---------------------------------------------------------------- kernel 4
// (R14 qtm verbatim) 2-product + register-prefetch staging.
__global__ __launch_bounds__(256) void qtm(
    const unsigned short* __restrict__ ahi,
    const unsigned short* __restrict__ xTh, const unsigned short* __restrict__ xTl,
    float* __restrict__ out)
{
  __shared__ char smem[27648];
  unsigned short* LAh = (unsigned short*)smem;   // [64][72]
  unsigned short* LBh = LAh + 64 * 72;
  unsigned short* LBl = LBh + 64 * 72;

  const int bid = blockIdx.x;
  const int b = bid / 48, t = bid % 48;
  const int m0 = (t % 6) * 64, n0 = (t / 6) * 64;
  const int tid = threadIdx.x;
  const int r = tid >> 2, kq = (tid & 3) * 16;
  const int w = tid >> 6, lane = tid & 63, quad = lane >> 4, l15 = lane & 15;
  const int mo = (w & 1) * 32, no = (w >> 1) * 32;
  f32x4 acc[2][2] = {};

  const unsigned short* Arh = ahi + ((size_t)(b * LYn + m0 + r)) * LXn + kq;
  const unsigned short* Brh = xTh + ((size_t)(b * Fn + n0 + r)) * LXn + kq;
  const unsigned short* Brl = xTl + ((size_t)(b * Fn + n0 + r)) * LXn + kq;
  uint4 pA0 = *(const uint4*)(Arh),     pA1 = *(const uint4*)(Arh + 8);
  uint4 pH0 = *(const uint4*)(Brh),     pH1 = *(const uint4*)(Brh + 8);
  uint4 pL0 = *(const uint4*)(Brl),     pL1 = *(const uint4*)(Brl + 8);

  for (int kc = 0; kc < LXn; kc += 64) {
    __syncthreads();
    *(uint4*)&LAh[r * 72 + kq]     = pA0;  *(uint4*)&LAh[r * 72 + kq + 8] = pA1;
    *(uint4*)&LBh[r * 72 + kq]     = pH0;  *(uint4*)&LBh[r * 72 + kq + 8] = pH1;
    *(uint4*)&LBl[r * 72 + kq]     = pL0;  *(uint4*)&LBl[r * 72 + kq + 8] = pL1;
    __syncthreads();
    if (kc + 64 < LXn) {
      pA0 = *(const uint4*)(Arh + kc + 64); pA1 = *(const uint4*)(Arh + kc + 72);
      pH0 = *(const uint4*)(Brh + kc + 64); pH1 = *(const uint4*)(Brh + kc + 72);
      pL0 = *(const uint4*)(Brl + kc + 64); pL1 = *(const uint4*)(Brl + kc + 72);
    }
    #pragma unroll
    for (int ko = 0; ko < 64; ko += 32) {
      bf16x8 ah[2], bh[2], bl[2];
      #pragma unroll
      for (int mi = 0; mi < 2; ++mi)
        ah[mi] = *(const bf16x8*)&LAh[(mo + mi * 16 + l15) * 72 + ko + quad * 8];
      #pragma unroll
      for (int nj = 0; nj < 2; ++nj) {
        int rb = (no + nj * 16 + l15) * 72 + ko + quad * 8;
        bh[nj] = *(const bf16x8*)&LBh[rb]; bl[nj] = *(const bf16x8*)&LBl[rb];
      }
      #pragma unroll
      for (int mi = 0; mi < 2; ++mi)
        #pragma unroll
        for (int nj = 0; nj < 2; ++nj) {
          acc[mi][nj] = __builtin_amdgcn_mfma_f32_16x16x32_bf16(ah[mi], bh[nj], acc[mi][nj], 0, 0, 0);
          acc[mi][nj] = __builtin_amdgcn_mfma_f32_16x16x32_bf16(ah[mi], bl[nj], acc[mi][nj], 0, 0, 0);
        }
    }
  }
  #pragma unroll
  for (int mi = 0; mi < 2; ++mi)
    #pragma unroll
    for (int nj = 0; nj < 2; ++nj)
      #pragma unroll
      for (int rr = 0; rr < 4; ++rr) {
        int row = m0 + mo + mi * 16 + quad * 4 + rr;
        int col = n0 + no + nj * 16 + l15;
        out[((size_t)(b * LYn + row)) * Fn + col] = acc[mi][nj][rr];
      }
}

extern "C" void kernel_launch(void* const* d_in, const int* in_sizes, int n_in,
                              void* d_out, int out_size, void* d_ws, size_t ws_size,
                              hipStream_t stream) {
  const float* x  = (const float*)d_in[0];
  const float* y  = (const float*)d_in[1];
  const float* Wm = (const float*)d_in[2];
  const float* vm = (const float*)d_in[3];
  float* outp = (float*)d_out;

  float* ey    = (float*)d_ws;                            // 393216 f32
  float* exT   = ey + 393216;                             // 393216 f32
  float* partS = exT + 393216;                            // 2*1536*384 f32 (4.7 MB)
  unsigned short* xTh = (unsigned short*)(partS + 2 * 1536 * 384);
  unsigned short* xTl = xTh + 786432;
  unsigned short* ahi = xTl + 786432;                     // total ~12 MB

  hipLaunchKernelGGL(gemm5, dim3(576), dim3(256), 0, stream, x, y, Wm, ey, exT, xTh, xTl);
  hipLaunchKernelGGL(score_part, dim3(128, 4), dim3(768), 0, stream, exT, ey, vm, partS);
  hipLaunchKernelGGL(sm_comb, dim3(192), dim3(512), 0, stream, partS, ahi);
  hipLaunchKernelGGL(qtm, dim3(192), dim3(256), 0, stream, ahi, xTh, xTl, outp);
}